// Round 3
// baseline (59.909 us; speedup 1.0000x reference)
//
#include <hip/hip_runtime.h>
#include <math.h>

#define DIM 1024
#define KK 7
#define DIL 2
#define BATCH 16384
#define NEG 0.01f

typedef float floatx4 __attribute__((ext_vector_type(4)));  // native vec for nt-store

// ---------------------------------------------------------------------------
// Fully fused: 1 block = 1 row of x (BATCH blocks x 256 threads, 4 features
// per thread). Per-feature scale + logdet tables are computed INLINE
// (~16 transcendental ops/thread ≈ 1.7 us of trans-pipe time chip-wide,
// hidden under the ~21 us HBM stream) — no precompute kernel, no second
// launch, no inter-kernel serialization bubble.
// ---------------------------------------------------------------------------
__global__ __launch_bounds__(256)
void cnn_flow_fused(const float* __restrict__ x,
                    const float* __restrict__ wgt,
                    const float* __restrict__ bias,
                    const float* __restrict__ lmbd,
                    float* __restrict__ out,
                    float* __restrict__ logdet) {
    const int b    = blockIdx.x;
    const int t    = threadIdx.x;
    const int base = t << 2;                 // 4 features per thread
    const float* xrow = x + (size_t)b * DIM;

    // weights + bias: wave-uniform scalar loads, L2-resident
    float w[KK];
#pragma unroll
    for (int k = 0; k < KK; ++k) w[k] = wgt[k];
    const float w0 = w[0];
    const float bs = bias[0];

    // 16-float conv window [base, base+16): features base..base+3 need taps
    // base .. base+3+12. Right zero-pad past DIM. 4 overlapping float4 loads;
    // the 3 redundant ones are same-block L1 hits (HBM fetch stays ~1x).
    float xv[16];
    if (base + 16 <= DIM) {
#pragma unroll
        for (int j = 0; j < 4; ++j) {
            float4 v = *reinterpret_cast<const float4*>(xrow + base + 4 * j);
            xv[4 * j + 0] = v.x; xv[4 * j + 1] = v.y;
            xv[4 * j + 2] = v.z; xv[4 * j + 3] = v.w;
        }
    } else {
#pragma unroll
        for (int j = 0; j < 16; ++j) {
            int idx = base + j;
            xv[j] = (idx < DIM) ? xrow[idx] : 0.0f;
        }
    }

    // per-feature tables, inline (sc = scale, lp/ln = logdet term for the
    // pos/neg leaky-relu branch)
    float sc[4], lp[4], ln[4];
    {
        float4 lm = *reinterpret_cast<const float4*>(lmbd + base);
        float lms[4] = {lm.x, lm.y, lm.z, lm.w};
        const float inv = (w0 != 0.0f) ? (-1.0f / w0) : 0.0f;
#pragma unroll
        for (int i = 0; i < 4; ++i) {
            float l  = lms[i];
            // jax.nn.softplus: max(x,0) + log1p(exp(-|x|))
            float sp = fmaxf(l, 0.0f) + log1pf(expf(-fabsf(l)));
            float scale;
            if (w0 == 0.0f)      scale = l;          // wave-uniform branch
            else if (w0 > 0.0f)  scale = inv + sp;
            else                 scale = inv - sp;
            sc[i] = scale;
            lp[i] = logf(fabsf(fmaf(scale,       w0, 1.0f)));
            ln[i] = logf(fabsf(fmaf(NEG * scale, w0, 1.0f)));
        }
    }

    float ld_acc = 0.0f;
    float o[4];
#pragma unroll
    for (int i = 0; i < 4; ++i) {
        float conv = bs;
#pragma unroll
        for (int k = 0; k < KK; ++k)
            conv = fmaf(xv[i + DIL * k], w[k], conv);
        bool pos  = (conv >= 0.0f);
        float act = pos ? conv : NEG * conv;
        o[i]      = fmaf(act, sc[i], xv[i]);
        ld_acc   += pos ? lp[i] : ln[i];
    }
    // out is never re-read: non-temporal store keeps the 64 MB write stream
    // from evicting x in L2. Native clang vector type for the builtin.
    floatx4 ov; ov.x = o[0]; ov.y = o[1]; ov.z = o[2]; ov.w = o[3];
    __builtin_nontemporal_store(ov,
        reinterpret_cast<floatx4*>(out + (size_t)b * DIM + base));

    // block-reduce logdet: wave64 shuffle tree, then 4-wave LDS combine
#pragma unroll
    for (int off = 32; off > 0; off >>= 1)
        ld_acc += __shfl_down(ld_acc, off, 64);
    __shared__ float red[4];
    const int wave = t >> 6;
    const int lane = t & 63;
    if (lane == 0) red[wave] = ld_acc;
    __syncthreads();
    if (t == 0)
        logdet[b] = (red[0] + red[1]) + (red[2] + red[3]);
}

extern "C" void kernel_launch(void* const* d_in, const int* in_sizes, int n_in,
                              void* d_out, int out_size, void* d_ws, size_t ws_size,
                              hipStream_t stream) {
    const float* x    = (const float*)d_in[0];
    const float* wgt  = (const float*)d_in[1];
    const float* bias = (const float*)d_in[2];
    const float* lmbd = (const float*)d_in[3];
    float* out    = (float*)d_out;                    // (BATCH, DIM)
    float* logdet = out + (size_t)BATCH * DIM;        // (BATCH,)

    cnn_flow_fused<<<BATCH, 256, 0, stream>>>(x, wgt, bias, lmbd, out, logdet);
}

// Round 4
// 33.388 us; speedup vs baseline: 1.7944x; 1.7944x over previous
//
#include <hip/hip_runtime.h>
#include <math.h>

#define DIM 1024
#define KK 7
#define DIL 2
#define BATCH 16384
#define NEG 0.01f
#define ROWS 16   // rows per block: amortizes the per-feature transcendental table

typedef float floatx4 __attribute__((ext_vector_type(4)));

// ---------------------------------------------------------------------------
// Single fused kernel. 1024 blocks x 256 threads; block b owns rows
// [b*ROWS, (b+1)*ROWS). Thread t owns features 4t..4t+3 for ALL its rows, so
// the per-feature scale/logdet table (4x expf/log1pf/logf each) is computed
// ONCE per block into registers and reused across ROWS rows -> transcendental
// work is 1/ROWS of the fully-fused version (~1.6 us chip-wide, hidden).
// ---------------------------------------------------------------------------
__global__ __launch_bounds__(256)
void cnn_flow_fused(const float* __restrict__ x,
                    const float* __restrict__ wgt,
                    const float* __restrict__ bias,
                    const float* __restrict__ lmbd,
                    float* __restrict__ out,
                    float* __restrict__ logdet) {
    const int t    = threadIdx.x;
    const int base = t << 2;                      // 4 features per thread
    const int row0 = blockIdx.x * ROWS;

    // weights + bias: wave-uniform scalar loads, L2-resident
    float w[KK];
#pragma unroll
    for (int k = 0; k < KK; ++k) w[k] = wgt[k];
    const float w0 = w[0];
    const float bs = bias[0];

    // per-feature tables, once per block (registers, reused for all ROWS rows)
    float sc[4], lp[4], ln[4];
    {
        float4 lm = *reinterpret_cast<const float4*>(lmbd + base);
        float lms[4] = {lm.x, lm.y, lm.z, lm.w};
        const float inv = (w0 != 0.0f) ? (-1.0f / w0) : 0.0f;
#pragma unroll
        for (int i = 0; i < 4; ++i) {
            float l  = lms[i];
            float sp = fmaxf(l, 0.0f) + log1pf(expf(-fabsf(l)));  // softplus
            float scale;
            if (w0 == 0.0f)      scale = l;       // wave-uniform branch
            else if (w0 > 0.0f)  scale = inv + sp;
            else                 scale = inv - sp;
            sc[i] = scale;
            lp[i] = logf(fabsf(fmaf(scale,       w0, 1.0f)));   // act_grad=1
            ln[i] = logf(fabsf(fmaf(NEG * scale, w0, 1.0f)));   // act_grad=NEG
        }
    }

    // conv window loader: 16 floats [base, base+16), right zero-pad past DIM.
    // 4 overlapping float4 loads; redundant ones are L1 hits (HBM ~1x).
    auto load_window = [&](const float* __restrict__ xrow, float* xv) {
        if (base + 16 <= DIM) {
#pragma unroll
            for (int j = 0; j < 4; ++j) {
                float4 v = *reinterpret_cast<const float4*>(xrow + base + 4 * j);
                xv[4 * j + 0] = v.x; xv[4 * j + 1] = v.y;
                xv[4 * j + 2] = v.z; xv[4 * j + 3] = v.w;
            }
        } else {
#pragma unroll
            for (int j = 0; j < 16; ++j) {
                int idx = base + j;
                xv[j] = (idx < DIM) ? xrow[idx] : 0.0f;
            }
        }
    };

    __shared__ float red[ROWS][4];                // per-row wave partials

    float xv[16];
    load_window(x + (size_t)row0 * DIM, xv);

    for (int r = 0; r < ROWS; ++r) {
        // prefetch next row while computing this one
        float xn[16];
        if (r + 1 < ROWS)
            load_window(x + (size_t)(row0 + r + 1) * DIM, xn);

        float ld_acc = 0.0f;
        float o[4];
#pragma unroll
        for (int i = 0; i < 4; ++i) {
            float conv = bs;
#pragma unroll
            for (int k = 0; k < KK; ++k)
                conv = fmaf(xv[i + DIL * k], w[k], conv);
            bool pos  = (conv >= 0.0f);
            float act = pos ? conv : NEG * conv;
            o[i]      = fmaf(act, sc[i], xv[i]);
            ld_acc   += pos ? lp[i] : ln[i];
        }
        floatx4 ov; ov.x = o[0]; ov.y = o[1]; ov.z = o[2]; ov.w = o[3];
        __builtin_nontemporal_store(ov,
            reinterpret_cast<floatx4*>(out + (size_t)(row0 + r) * DIM + base));

        // wave64 shuffle reduce; lane 0 of each wave parks partial in LDS
#pragma unroll
        for (int off = 32; off > 0; off >>= 1)
            ld_acc += __shfl_down(ld_acc, off, 64);
        if ((t & 63) == 0) red[r][t >> 6] = ld_acc;

#pragma unroll
        for (int j = 0; j < 16; ++j) xv[j] = xn[j];
    }

    __syncthreads();                              // single barrier per block
    if (t < ROWS) {
        float v = (red[t][0] + red[t][1]) + (red[t][2] + red[t][3]);
        logdet[row0 + t] = v;
    }
}

extern "C" void kernel_launch(void* const* d_in, const int* in_sizes, int n_in,
                              void* d_out, int out_size, void* d_ws, size_t ws_size,
                              hipStream_t stream) {
    const float* x    = (const float*)d_in[0];
    const float* wgt  = (const float*)d_in[1];
    const float* bias = (const float*)d_in[2];
    const float* lmbd = (const float*)d_in[3];
    float* out    = (float*)d_out;                    // (BATCH, DIM)
    float* logdet = out + (size_t)BATCH * DIM;        // (BATCH,)

    cnn_flow_fused<<<BATCH / ROWS, 256, 0, stream>>>(x, wgt, bias, lmbd, out, logdet);
}

// Round 5
// 29.424 us; speedup vs baseline: 2.0361x; 1.1347x over previous
//
#include <hip/hip_runtime.h>
#include <math.h>

#define DIM 1024
#define KK 7
#define DIL 2
#define BATCH 16384
#define NEG 0.01f
#define ROWS 8    // rows per block: amortizes trans table 8x, keeps grid at
                  // 2048 blocks = 8 blocks/CU = 32 waves/CU (100% theoretical)

typedef float floatx4 __attribute__((ext_vector_type(4)));

// ---------------------------------------------------------------------------
// Single fused kernel. 2048 blocks x 256 threads; block b owns rows
// [b*ROWS, (b+1)*ROWS). Thread t owns features 4t..4t+3 for ALL its rows:
// the per-feature scale/logdet table (4x expf/log1pf/logf each) is computed
// once per block into registers and reused across ROWS rows (~3 us chip-wide
// trans work, hidden under the memory stream). Row loop fully unrolled so the
// 1-ahead prefetch is register-renamed (no copy chain).
// ---------------------------------------------------------------------------
__global__ __launch_bounds__(256)
void cnn_flow_fused(const float* __restrict__ x,
                    const float* __restrict__ wgt,
                    const float* __restrict__ bias,
                    const float* __restrict__ lmbd,
                    float* __restrict__ out,
                    float* __restrict__ logdet) {
    const int t    = threadIdx.x;
    const int base = t << 2;                      // 4 features per thread
    const int row0 = blockIdx.x * ROWS;

    // weights + bias: wave-uniform scalar loads, L2-resident
    float w[KK];
#pragma unroll
    for (int k = 0; k < KK; ++k) w[k] = wgt[k];
    const float w0 = w[0];
    const float bs = bias[0];

    // per-feature tables, once per block (registers, reused for all ROWS rows)
    float sc[4], lp[4], ln[4];
    {
        float4 lm = *reinterpret_cast<const float4*>(lmbd + base);
        float lms[4] = {lm.x, lm.y, lm.z, lm.w};
        const float inv = (w0 != 0.0f) ? (-1.0f / w0) : 0.0f;
#pragma unroll
        for (int i = 0; i < 4; ++i) {
            float l  = lms[i];
            float sp = fmaxf(l, 0.0f) + log1pf(expf(-fabsf(l)));  // softplus
            float scale;
            if (w0 == 0.0f)      scale = l;       // wave-uniform branch
            else if (w0 > 0.0f)  scale = inv + sp;
            else                 scale = inv - sp;
            sc[i] = scale;
            lp[i] = logf(fabsf(fmaf(scale,       w0, 1.0f)));   // act_grad=1
            ln[i] = logf(fabsf(fmaf(NEG * scale, w0, 1.0f)));   // act_grad=NEG
        }
    }

    // conv window loader: 16 floats [base, base+16), right zero-pad past DIM.
    // 4 overlapping float4 loads; redundant ones are L1 hits (HBM ~1x).
    auto load_window = [&](const float* __restrict__ xrow, float* xv) {
        if (base + 16 <= DIM) {
#pragma unroll
            for (int j = 0; j < 4; ++j) {
                float4 v = *reinterpret_cast<const float4*>(xrow + base + 4 * j);
                xv[4 * j + 0] = v.x; xv[4 * j + 1] = v.y;
                xv[4 * j + 2] = v.z; xv[4 * j + 3] = v.w;
            }
        } else {
#pragma unroll
            for (int j = 0; j < 16; ++j) {
                int idx = base + j;
                xv[j] = (idx < DIM) ? xrow[idx] : 0.0f;
            }
        }
    };

    __shared__ float red[ROWS][4];                // per-row wave partials

    float xv[16];
    load_window(x + (size_t)row0 * DIM, xv);

#pragma unroll
    for (int r = 0; r < ROWS; ++r) {
        // 1-ahead prefetch; full unroll -> xn is register-renamed, no copies
        float xn[16];
        if (r + 1 < ROWS)
            load_window(x + (size_t)(row0 + r + 1) * DIM, xn);

        float ld_acc = 0.0f;
        float o[4];
#pragma unroll
        for (int i = 0; i < 4; ++i) {
            float conv = bs;
#pragma unroll
            for (int k = 0; k < KK; ++k)
                conv = fmaf(xv[i + DIL * k], w[k], conv);
            bool pos  = (conv >= 0.0f);
            float act = pos ? conv : NEG * conv;
            o[i]      = fmaf(act, sc[i], xv[i]);
            ld_acc   += pos ? lp[i] : ln[i];
        }
        floatx4 ov; ov.x = o[0]; ov.y = o[1]; ov.z = o[2]; ov.w = o[3];
        __builtin_nontemporal_store(ov,
            reinterpret_cast<floatx4*>(out + (size_t)(row0 + r) * DIM + base));

        // wave64 shuffle reduce; lane 0 of each wave parks partial in LDS
#pragma unroll
        for (int off = 32; off > 0; off >>= 1)
            ld_acc += __shfl_down(ld_acc, off, 64);
        if ((t & 63) == 0) red[r][t >> 6] = ld_acc;

        if (r + 1 < ROWS) {
#pragma unroll
            for (int j = 0; j < 16; ++j) xv[j] = xn[j];
        }
    }

    __syncthreads();                              // single barrier per block
    if (t < ROWS) {
        float v = (red[t][0] + red[t][1]) + (red[t][2] + red[t][3]);
        logdet[row0 + t] = v;
    }
}

extern "C" void kernel_launch(void* const* d_in, const int* in_sizes, int n_in,
                              void* d_out, int out_size, void* d_ws, size_t ws_size,
                              hipStream_t stream) {
    const float* x    = (const float*)d_in[0];
    const float* wgt  = (const float*)d_in[1];
    const float* bias = (const float*)d_in[2];
    const float* lmbd = (const float*)d_in[3];
    float* out    = (float*)d_out;                    // (BATCH, DIM)
    float* logdet = out + (size_t)BATCH * DIM;        // (BATCH,)

    cnn_flow_fused<<<BATCH / ROWS, 256, 0, stream>>>(x, wgt, bias, lmbd, out, logdet);
}

// Round 6
// 29.293 us; speedup vs baseline: 2.0452x; 1.0045x over previous
//
#include <hip/hip_runtime.h>
#include <math.h>

#define DIM 1024
#define KK 7
#define DIL 2
#define BATCH 16384
#define NEG 0.01f
#define ROWS 8    // rows per block: amortizes trans table, grid = 2048 blocks

typedef float floatx4 __attribute__((ext_vector_type(4)));

// ---------------------------------------------------------------------------
// Single fused kernel. 2048 blocks x 256 threads; block b owns rows
// [b*ROWS, (b+1)*ROWS). Thread t owns features 4t..4t+3 for ALL its rows.
// Per-feature scale/logdet tables: once per block, in registers.
// Logdet: row loop only does a fire-and-forget ds_write of the per-thread
// partial (no cross-lane chain in the hot loop); one barrier + per-wave
// shuffle-tree reduce at block end. Keeps the row loop a pure
// load -> FMA -> store stream.
// ---------------------------------------------------------------------------
__global__ __launch_bounds__(256)
void cnn_flow_fused(const float* __restrict__ x,
                    const float* __restrict__ wgt,
                    const float* __restrict__ bias,
                    const float* __restrict__ lmbd,
                    float* __restrict__ out,
                    float* __restrict__ logdet) {
    const int t    = threadIdx.x;
    const int base = t << 2;                      // 4 features per thread
    const int row0 = blockIdx.x * ROWS;

    // weights + bias: wave-uniform scalar loads, L2-resident
    float w[KK];
#pragma unroll
    for (int k = 0; k < KK; ++k) w[k] = wgt[k];
    const float w0 = w[0];
    const float bs = bias[0];

    // per-feature tables, once per block (registers, reused for all ROWS rows)
    float sc[4], lp[4], ln[4];
    {
        float4 lm = *reinterpret_cast<const float4*>(lmbd + base);
        float lms[4] = {lm.x, lm.y, lm.z, lm.w};
        const float inv = (w0 != 0.0f) ? (-1.0f / w0) : 0.0f;
#pragma unroll
        for (int i = 0; i < 4; ++i) {
            float l  = lms[i];
            float sp = fmaxf(l, 0.0f) + log1pf(expf(-fabsf(l)));  // softplus
            float scale;
            if (w0 == 0.0f)      scale = l;       // wave-uniform branch
            else if (w0 > 0.0f)  scale = inv + sp;
            else                 scale = inv - sp;
            sc[i] = scale;
            lp[i] = logf(fabsf(fmaf(scale,       w0, 1.0f)));   // act_grad=1
            ln[i] = logf(fabsf(fmaf(NEG * scale, w0, 1.0f)));   // act_grad=NEG
        }
    }

    // conv window loader: 16 floats [base, base+16), right zero-pad past DIM.
    // 4 overlapping float4 loads; redundant ones are L1 hits (HBM ~1x).
    auto load_window = [&](const float* __restrict__ xrow, float* xv) {
        if (base + 16 <= DIM) {
#pragma unroll
            for (int j = 0; j < 4; ++j) {
                float4 v = *reinterpret_cast<const float4*>(xrow + base + 4 * j);
                xv[4 * j + 0] = v.x; xv[4 * j + 1] = v.y;
                xv[4 * j + 2] = v.z; xv[4 * j + 3] = v.w;
            }
        } else {
#pragma unroll
            for (int j = 0; j < 16; ++j) {
                int idx = base + j;
                xv[j] = (idx < DIM) ? xrow[idx] : 0.0f;
            }
        }
    };

    __shared__ float red[ROWS][256];              // per-thread partials, 8 KB

    float xv[16];
    load_window(x + (size_t)row0 * DIM, xv);

#pragma unroll
    for (int r = 0; r < ROWS; ++r) {
        // 1-ahead prefetch; full unroll -> xn is register-renamed
        float xn[16];
        if (r + 1 < ROWS)
            load_window(x + (size_t)(row0 + r + 1) * DIM, xn);

        float ld_acc = 0.0f;
        float o[4];
#pragma unroll
        for (int i = 0; i < 4; ++i) {
            float conv = bs;
#pragma unroll
            for (int k = 0; k < KK; ++k)
                conv = fmaf(xv[i + DIL * k], w[k], conv);
            bool pos  = (conv >= 0.0f);
            float act = pos ? conv : NEG * conv;
            o[i]      = fmaf(act, sc[i], xv[i]);
            ld_acc   += pos ? lp[i] : ln[i];
        }
        floatx4 ov; ov.x = o[0]; ov.y = o[1]; ov.z = o[2]; ov.w = o[3];
        __builtin_nontemporal_store(ov,
            reinterpret_cast<floatx4*>(out + (size_t)(row0 + r) * DIM + base));

        // fire-and-forget stash (conflict-free: thread t -> word t)
        red[r][t] = ld_acc;

        if (r + 1 < ROWS) {
#pragma unroll
            for (int j = 0; j < 16; ++j) xv[j] = xn[j];
        }
    }

    __syncthreads();                              // single barrier per block

    // end-of-block reduce: wave wv handles rows {wv, wv+4}. Lane l reads 4
    // strided partials (2-way bank alias = free), one 6-deep shuffle tree.
    const int wv   = t >> 6;
    const int lane = t & 63;
#pragma unroll
    for (int rr = 0; rr < 2; ++rr) {
        const int r = wv + 4 * rr;
        float v = red[r][lane] + red[r][lane + 64] +
                  red[r][lane + 128] + red[r][lane + 192];
#pragma unroll
        for (int off = 32; off > 0; off >>= 1)
            v += __shfl_down(v, off, 64);
        if (lane == 0) logdet[row0 + r] = v;
    }
}

extern "C" void kernel_launch(void* const* d_in, const int* in_sizes, int n_in,
                              void* d_out, int out_size, void* d_ws, size_t ws_size,
                              hipStream_t stream) {
    const float* x    = (const float*)d_in[0];
    const float* wgt  = (const float*)d_in[1];
    const float* bias = (const float*)d_in[2];
    const float* lmbd = (const float*)d_in[3];
    float* out    = (float*)d_out;                    // (BATCH, DIM)
    float* logdet = out + (size_t)BATCH * DIM;        // (BATCH,)

    cnn_flow_fused<<<BATCH / ROWS, 256, 0, stream>>>(x, wgt, bias, lmbd, out, logdet);
}

// Round 7
// 28.532 us; speedup vs baseline: 2.0998x; 1.0267x over previous
//
#include <hip/hip_runtime.h>
#include <math.h>

#define DIM 1024
#define KK 7
#define DIL 2
#define BATCH 16384
#define NEG 0.01f
#define ROWS 8      // rows per block
#define RPAD 1040   // LDS row stride in floats: 1024 + 16 zero-pad (kills tail branch)

typedef float floatx4 __attribute__((ext_vector_type(4)));

// Direct global->LDS DMA, 16B per lane, no VGPR round-trip.
__device__ __forceinline__ void gload_lds16(const float* g, float* l) {
    __builtin_amdgcn_global_load_lds(
        (const __attribute__((address_space(1))) void*)g,
        (__attribute__((address_space(3))) void*)l,
        16 /* bytes, literal */, 0, 0);
}

// ---------------------------------------------------------------------------
// 2048 blocks x 256 threads; block b owns rows [b*8, b*8+8).
// Phase 1: issue ALL 8 rows' global_load_lds (8 KB in flight per wave,
//          1x read traffic, zero VGPR) + zero the 64B/row LDS pad; compute
//          the per-feature transcendental table while loads are in flight.
// Phase 2: one __syncthreads, then stream: 4x ds_read_b128 window ->
//          28 FMA conv -> leaky-relu/scale/skip -> nt-store; per-row wave
//          shuffle reduce for logdet.
// ---------------------------------------------------------------------------
__global__ __launch_bounds__(256)
void cnn_flow_fused(const float* __restrict__ x,
                    const float* __restrict__ wgt,
                    const float* __restrict__ bias,
                    const float* __restrict__ lmbd,
                    float* __restrict__ out,
                    float* __restrict__ logdet) {
    const int t    = threadIdx.x;
    const int wv   = t >> 6;
    const int lane = t & 63;
    const int base = t << 2;                      // 4 features per thread
    const int row0 = blockIdx.x * ROWS;

    __shared__ float sx[ROWS * RPAD];             // 33280 B staging
    __shared__ float red[ROWS][4];                // per-row wave partials

    // ---- Phase 1: issue all row loads (wave w covers floats [w*256,w*256+256))
    {
        const float* g0 = x + (size_t)row0 * DIM + (wv << 8) + (lane << 2);
        float*       l0 = sx + (wv << 8) + (lane << 2);
#pragma unroll
        for (int r = 0; r < ROWS; ++r)
            gload_lds16(g0 + r * DIM, l0 + r * RPAD);
    }
    // zero the 16-float pad of each row: threads 0..31 -> row t>>2, chunk t&3
    if (t < ROWS * 4) {
        *reinterpret_cast<float4*>(sx + (t >> 2) * RPAD + DIM + ((t & 3) << 2)) =
            make_float4(0.f, 0.f, 0.f, 0.f);
    }

    // weights + bias (L2-resident scalar loads)
    float w[KK];
#pragma unroll
    for (int k = 0; k < KK; ++k) w[k] = wgt[k];
    const float w0 = w[0];
    const float bs = bias[0];

    // per-feature tables, once per block — overlaps the in-flight row loads
    float sc[4], lp[4], ln[4];
    {
        float4 lm = *reinterpret_cast<const float4*>(lmbd + base);
        float lms[4] = {lm.x, lm.y, lm.z, lm.w};
        const float inv = (w0 != 0.0f) ? (-1.0f / w0) : 0.0f;
#pragma unroll
        for (int i = 0; i < 4; ++i) {
            float l  = lms[i];
            float sp = fmaxf(l, 0.0f) + log1pf(expf(-fabsf(l)));  // softplus
            float scale;
            if (w0 == 0.0f)      scale = l;
            else if (w0 > 0.0f)  scale = inv + sp;
            else                 scale = inv - sp;
            sc[i] = scale;
            lp[i] = logf(fabsf(fmaf(scale,       w0, 1.0f)));   // act_grad=1
            ln[i] = logf(fabsf(fmaf(NEG * scale, w0, 1.0f)));   // act_grad=NEG
        }
    }

    __syncthreads();   // drains vmcnt (global_load_lds) + lgkmcnt (pad writes)

    // ---- Phase 2: stream rows out of LDS
#pragma unroll
    for (int r = 0; r < ROWS; ++r) {
        const float* srow = sx + r * RPAD + base;
        float xv[16];
#pragma unroll
        for (int j = 0; j < 4; ++j) {            // 4x ds_read_b128, 2-way alias
            float4 v = *reinterpret_cast<const float4*>(srow + 4 * j);
            xv[4 * j + 0] = v.x; xv[4 * j + 1] = v.y;
            xv[4 * j + 2] = v.z; xv[4 * j + 3] = v.w;
        }

        float ld_acc = 0.0f;
        float o[4];
#pragma unroll
        for (int i = 0; i < 4; ++i) {
            float conv = bs;
#pragma unroll
            for (int k = 0; k < KK; ++k)
                conv = fmaf(xv[i + DIL * k], w[k], conv);
            bool pos  = (conv >= 0.0f);
            float act = pos ? conv : NEG * conv;
            o[i]      = fmaf(act, sc[i], xv[i]);
            ld_acc   += pos ? lp[i] : ln[i];
        }
        floatx4 ov; ov.x = o[0]; ov.y = o[1]; ov.z = o[2]; ov.w = o[3];
        __builtin_nontemporal_store(ov,
            reinterpret_cast<floatx4*>(out + (size_t)(row0 + r) * DIM + base));

        // wave shuffle reduce (latency hidden per R6 A/B); lane 0 parks partial
#pragma unroll
        for (int off = 32; off > 0; off >>= 1)
            ld_acc += __shfl_down(ld_acc, off, 64);
        if (lane == 0) red[r][wv] = ld_acc;
    }

    __syncthreads();
    if (t < ROWS)
        logdet[row0 + t] = (red[t][0] + red[t][1]) + (red[t][2] + red[t][3]);
}

extern "C" void kernel_launch(void* const* d_in, const int* in_sizes, int n_in,
                              void* d_out, int out_size, void* d_ws, size_t ws_size,
                              hipStream_t stream) {
    const float* x    = (const float*)d_in[0];
    const float* wgt  = (const float*)d_in[1];
    const float* bias = (const float*)d_in[2];
    const float* lmbd = (const float*)d_in[3];
    float* out    = (float*)d_out;                    // (BATCH, DIM)
    float* logdet = out + (size_t)BATCH * DIM;        // (BATCH,)

    cnn_flow_fused<<<BATCH / ROWS, 256, 0, stream>>>(x, wgt, bias, lmbd, out, logdet);
}